// Round 8
// baseline (1342.572 us; speedup 1.0000x reference)
//
#include <hip/hip_runtime.h>
#include <math.h>

#define BDIM 8
#define IMG 224
#define PP 16
#define GG 14
#define NN 196
#define PD 256
#define DD 128
#define DFFV 256
#define CC 1000
#define NBLK 784

#define NEGINF (-INFINITY)

struct KArgs {
  const float *x, *eW, *pos;
  const float *qW0, *kW0, *vW0, *f1W0, *f2W0, *tau0;
  const float *qW1, *kW1, *vW1, *f1W1, *f2W1, *tau1;
  const float *hW, *ls;
  float *q0, *k0, *v0, *q1, *k1, *v1, *pp, *out;
  unsigned *cnt;
};

// Software grid barrier: cumulative counter (zeroed by hipMemsetAsync each
// launch). Release/acquire via __threadfence (device scope: L2 wb/inv for
// cross-XCD visibility); arrival+poll via device-scope atomics (m20).
__device__ inline void grid_barrier(unsigned* cnt, unsigned target) {
  __syncthreads();
  if (threadIdx.x == 0) {
    __threadfence();
    __hip_atomic_fetch_add(cnt, 1u, __ATOMIC_RELEASE, __HIP_MEMORY_SCOPE_AGENT);
    while (__hip_atomic_load(cnt, __ATOMIC_ACQUIRE, __HIP_MEMORY_SCOPE_AGENT) < target)
      __builtin_amdgcn_s_sleep(4);
    __threadfence();
  }
  __syncthreads();
}

// thread (row = t>>7, d = t&127) computes output col d of its row from LDS
// activations (broadcast reads) + per-thread float4 W row.
#define QKV_PASS(W, DST, SAVEQ)                                                   \
  {                                                                               \
    const float4* W4 = reinterpret_cast<const float4*>((W) + (size_t)d * DD);     \
    float acc = NEGINF;                                                           \
    _Pragma("unroll 4") for (int j4 = 0; j4 < DD / 4; j4++) {                     \
      float4 w = W4[j4];                                                          \
      int j = j4 * 4;                                                             \
      acc = fmaxf(acc, hs[row][j + 0] + w.x);                                     \
      acc = fmaxf(acc, hs[row][j + 1] + w.y);                                     \
      acc = fmaxf(acc, hs[row][j + 2] + w.z);                                     \
      acc = fmaxf(acc, hs[row][j + 3] + w.w);                                     \
    }                                                                             \
    float o = acc - hm2[row];                                                     \
    (DST)[(size_t)(r0 + row) * DD + d] = o;                                       \
    if (SAVEQ) qs[row][d] = o;                                                    \
  }

__global__ __launch_bounds__(256, 4) void fused_kernel(KArgs a) {
  const int blk = blockIdx.x;
  const int t = threadIdx.x;
  const int r0 = blk * 2;
  const int b = r0 / NN;
  const int n0 = r0 % NN;  // even; never crosses batch boundary (NN even)
  const int row = t >> 7;  // waves 0,1 -> row 0; waves 2,3 -> row 1
  const int d = t & 127;
  const int lane = t & 63;
  const int wv = t >> 6;

  __shared__ float hs[2][DD];
  __shared__ float qs[2][DD];
  __shared__ float sc[2][NN];
  __shared__ float gs[2][DFFV];
  __shared__ float comb[2][2][DD];
  __shared__ float redA[4];
  __shared__ float hm2[2];
  __shared__ float plds[8][DD];
  __shared__ float gred[8][32];

  // ================= Stage A: embed (2 rows) =================
  {
    int n = n0 + row;
    int gi = n / GG, gj = n % GG;
    const float* xb = a.x + (size_t)b * IMG * IMG + (size_t)(gi * PP) * IMG + gj * PP;
    const float4* W4 = reinterpret_cast<const float4*>(a.eW + (size_t)d * PD);
    float acc = NEGINF;
#pragma unroll 4
    for (int j4 = 0; j4 < PD / 4; j4++) {
      float4 w = W4[j4];
      int j = j4 * 4, pi = j >> 4, pj = j & 15;
      const float* xr = xb + (size_t)pi * IMG + pj;
      acc = fmaxf(acc, xr[0] + w.x); acc = fmaxf(acc, xr[1] + w.y);
      acc = fmaxf(acc, xr[2] + w.z); acc = fmaxf(acc, xr[3] + w.w);
    }
    float hv = acc + a.pos[(size_t)n * DD + d];
    hs[row][d] = hv;
    float m = hv;
#pragma unroll
    for (int mask = 32; mask >= 1; mask >>= 1) m = fmaxf(m, __shfl_xor(m, mask));
    if (lane == 0) redA[wv] = m;
  }
  __syncthreads();
  if (t < 2) hm2[t] = fmaxf(redA[t * 2], redA[t * 2 + 1]);
  __syncthreads();

  // qkv layer 0
  QKV_PASS(a.qW0, a.q0, 1)
  QKV_PASS(a.kW0, a.k0, 0)
  QKV_PASS(a.vW0, a.v0, 0)

  grid_barrier(a.cnt, NBLK);

  // ============ layer body: attn + ffn (row-local, h in LDS) ============
  auto layer = [&](const float* kbuf, const float* vbuf, const float* f1W,
                   const float* f2W, const float* tauP) {
    // --- scores: thread t = key index j ---
    if (t < NN) {
      const float4* k4 = reinterpret_cast<const float4*>(kbuf + ((size_t)b * NN + t) * DD);
      float a0 = NEGINF, a1 = NEGINF;
#pragma unroll 4
      for (int d4 = 0; d4 < DD / 4; d4++) {
        float4 kv = k4[d4];
        int dd = d4 * 4;
        a0 = fmaxf(a0, qs[0][dd + 0] + kv.x); a0 = fmaxf(a0, qs[0][dd + 1] + kv.y);
        a0 = fmaxf(a0, qs[0][dd + 2] + kv.z); a0 = fmaxf(a0, qs[0][dd + 3] + kv.w);
        a1 = fmaxf(a1, qs[1][dd + 0] + kv.x); a1 = fmaxf(a1, qs[1][dd + 1] + kv.y);
        a1 = fmaxf(a1, qs[1][dd + 2] + kv.z); a1 = fmaxf(a1, qs[1][dd + 3] + kv.w);
      }
      sc[0][t] = a0; sc[1][t] = a1;
    }
    __syncthreads();
    // --- PV: split j-range over the two row-halves ---
    {
      int jh = row;
      const float* vb = vbuf + (size_t)b * NN * DD;
      float a0 = NEGINF, a1 = NEGINF;
#pragma unroll 4
      for (int j = jh * 98; j < jh * 98 + 98; j++) {
        float vv = vb[(size_t)j * DD + d];
        a0 = fmaxf(a0, sc[0][j] + vv);
        a1 = fmaxf(a1, sc[1][j] + vv);
      }
      comb[jh][0][d] = a0; comb[jh][1][d] = a1;
    }
    __syncthreads();
    // --- combine + pnorm + residual + new rowmax ---
    {
      float f = fmaxf(comb[0][row][d], comb[1][row][d]);
      float m = f;
#pragma unroll
      for (int mask = 32; mask >= 1; mask >>= 1) m = fmaxf(m, __shfl_xor(m, mask));
      if (lane == 0) redA[wv] = m;
      __syncthreads();
      float amax = fmaxf(redA[row * 2], redA[row * 2 + 1]);
      float hv = fmaxf(hs[row][d], f - amax);
      hs[row][d] = hv;
      float m2v = hv;
#pragma unroll
      for (int mask = 32; mask >= 1; mask >>= 1) m2v = fmaxf(m2v, __shfl_xor(m2v, mask));
      if (lane == 0) redA[wv] = m2v;
      __syncthreads();
      if (t < 2) hm2[t] = fmaxf(redA[t * 2], redA[t * 2 + 1]);
    }
    __syncthreads();
    // --- ffn1: thread t = DFF col, both rows ---
    {
      float tv = tauP[0];
      const float4* W4 = reinterpret_cast<const float4*>(f1W + (size_t)t * DD);
      float a0 = NEGINF, a1 = NEGINF;
#pragma unroll 4
      for (int j4 = 0; j4 < DD / 4; j4++) {
        float4 w = W4[j4];
        int j = j4 * 4;
        a0 = fmaxf(a0, hs[0][j + 0] + w.x); a0 = fmaxf(a0, hs[0][j + 1] + w.y);
        a0 = fmaxf(a0, hs[0][j + 2] + w.z); a0 = fmaxf(a0, hs[0][j + 3] + w.w);
        a1 = fmaxf(a1, hs[1][j + 0] + w.x); a1 = fmaxf(a1, hs[1][j + 1] + w.y);
        a1 = fmaxf(a1, hs[1][j + 2] + w.z); a1 = fmaxf(a1, hs[1][j + 3] + w.w);
      }
      gs[0][t] = fmaxf(a0 - hm2[0], tv);
      gs[1][t] = fmaxf(a1 - hm2[1], tv);
    }
    __syncthreads();
    // --- ffn2: thread (kh=row, i=d): half of DFF per thread, both rows ---
    {
      int kh = row;
      const float4* W4 = reinterpret_cast<const float4*>(f2W + (size_t)d * DFFV) + kh * 32;
      float a0 = NEGINF, a1 = NEGINF;
#pragma unroll 4
      for (int j4 = 0; j4 < 32; j4++) {
        float4 w = W4[j4];
        int j = kh * 128 + j4 * 4;
        a0 = fmaxf(a0, gs[0][j + 0] + w.x); a0 = fmaxf(a0, gs[0][j + 1] + w.y);
        a0 = fmaxf(a0, gs[0][j + 2] + w.z); a0 = fmaxf(a0, gs[0][j + 3] + w.w);
        a1 = fmaxf(a1, gs[1][j + 0] + w.x); a1 = fmaxf(a1, gs[1][j + 1] + w.y);
        a1 = fmaxf(a1, gs[1][j + 2] + w.z); a1 = fmaxf(a1, gs[1][j + 3] + w.w);
      }
      comb[kh][0][d] = a0; comb[kh][1][d] = a1;
    }
    __syncthreads();
    // --- combine + pnorm + residual + new rowmax ---
    {
      float f = fmaxf(comb[0][row][d], comb[1][row][d]);
      float m = f;
#pragma unroll
      for (int mask = 32; mask >= 1; mask >>= 1) m = fmaxf(m, __shfl_xor(m, mask));
      if (lane == 0) redA[wv] = m;
      __syncthreads();
      float fmx = fmaxf(redA[row * 2], redA[row * 2 + 1]);
      float hv = fmaxf(hs[row][d], f - fmx);
      hs[row][d] = hv;
      float m2v = hv;
#pragma unroll
      for (int mask = 32; mask >= 1; mask >>= 1) m2v = fmaxf(m2v, __shfl_xor(m2v, mask));
      if (lane == 0) redA[wv] = m2v;
      __syncthreads();
      if (t < 2) hm2[t] = fmaxf(redA[t * 2], redA[t * 2 + 1]);
    }
    __syncthreads();
  };

  // ================= Stage B: layer 0 + qkv layer 1 =================
  layer(a.k0, a.v0, a.f1W0, a.f2W0, a.tau0);
  QKV_PASS(a.qW1, a.q1, 1)
  QKV_PASS(a.kW1, a.k1, 0)
  QKV_PASS(a.vW1, a.v1, 0)

  grid_barrier(a.cnt, 2 * NBLK);

  // ================= Stage C: layer 1 + partial pool =================
  layer(a.k1, a.v1, a.f1W1, a.f2W1, a.tau1);
  if (t < DD) a.pp[(size_t)blk * DD + t] = fmaxf(hs[0][t], hs[1][t]);

  grid_barrier(a.cnt, 3 * NBLK);

  // ================= Stage D: head (blocks 0..255) =================
  if (blk < 256) {
    int cc = blk & 31, bb = blk >> 5;
    {
      int d4 = t & 31, ng = t >> 5;
      float4 pm = {NEGINF, NEGINF, NEGINF, NEGINF};
      for (int g = bb * 98 + ng; g < (bb + 1) * 98; g += 8) {
        float4 hv = *reinterpret_cast<const float4*>(a.pp + (size_t)g * DD + d4 * 4);
        pm.x = fmaxf(pm.x, hv.x); pm.y = fmaxf(pm.y, hv.y);
        pm.z = fmaxf(pm.z, hv.z); pm.w = fmaxf(pm.w, hv.w);
      }
      *reinterpret_cast<float4*>(&plds[ng][d4 * 4]) = pm;
    }
    __syncthreads();
    if (t < DD) {
      float m = plds[0][t];
#pragma unroll
      for (int g2 = 1; g2 < 8; g2++) m = fmaxf(m, plds[g2][t]);
      hs[0][t] = m;  // pooled
    }
    __syncthreads();
    int cl = t & 31, ds = t >> 5;
    int c = cc * 32 + cl;
    float acc = NEGINF;
    if (c < CC) {
      const float4* W4 = reinterpret_cast<const float4*>(a.hW + (size_t)c * DD) + ds * 4;
#pragma unroll
      for (int kk = 0; kk < 4; kk++) {
        float4 w = W4[kk];
        int db = ds * 16 + kk * 4;
        acc = fmaxf(acc, hs[0][db + 0] + w.x);
        acc = fmaxf(acc, hs[0][db + 1] + w.y);
        acc = fmaxf(acc, hs[0][db + 2] + w.z);
        acc = fmaxf(acc, hs[0][db + 3] + w.w);
      }
    }
    gred[ds][cl] = acc;
    __syncthreads();
    if (t < 32) {
      int c2 = cc * 32 + t;
      if (c2 < CC) {
        float m = gred[0][t];
#pragma unroll
        for (int g2 = 1; g2 < 8; g2++) m = fmaxf(m, gred[g2][t]);
        a.out[(size_t)bb * CC + c2] = m * a.ls[0];
      }
    }
  }
}

extern "C" void kernel_launch(void* const* d_in, const int* in_sizes, int n_in,
                              void* d_out, int out_size, void* d_ws, size_t ws_size,
                              hipStream_t stream) {
  // ws layout: [0..63] barrier counter (cache-line isolated), then float bufs
  unsigned* cnt = (unsigned*)d_ws;
  float* ws = (float*)d_ws + 64;
  size_t o = 0;
  float* q0 = ws + o; o += (size_t)NBLK * 2 * DD;
  float* k0 = ws + o; o += (size_t)NBLK * 2 * DD;
  float* v0 = ws + o; o += (size_t)NBLK * 2 * DD;
  float* q1 = ws + o; o += (size_t)NBLK * 2 * DD;
  float* k1 = ws + o; o += (size_t)NBLK * 2 * DD;
  float* v1 = ws + o; o += (size_t)NBLK * 2 * DD;
  float* pp = ws + o; o += (size_t)NBLK * DD;

  hipMemsetAsync(d_ws, 0, 256, stream);  // zero barrier counter (graph-safe)

  KArgs ka;
  ka.x = (const float*)d_in[0];
  ka.eW = (const float*)d_in[1];
  ka.pos = (const float*)d_in[2];
  ka.qW0 = (const float*)d_in[3];
  ka.kW0 = (const float*)d_in[4];
  ka.vW0 = (const float*)d_in[5];
  ka.f1W0 = (const float*)d_in[6];
  ka.f2W0 = (const float*)d_in[7];
  ka.tau0 = (const float*)d_in[8];
  ka.qW1 = (const float*)d_in[9];
  ka.kW1 = (const float*)d_in[10];
  ka.vW1 = (const float*)d_in[11];
  ka.f1W1 = (const float*)d_in[12];
  ka.f2W1 = (const float*)d_in[13];
  ka.tau1 = (const float*)d_in[14];
  ka.hW = (const float*)d_in[15];
  ka.ls = (const float*)d_in[16];
  ka.q0 = q0; ka.k0 = k0; ka.v0 = v0;
  ka.q1 = q1; ka.k1 = k1; ka.v1 = v1;
  ka.pp = pp;
  ka.out = (float*)d_out;
  ka.cnt = cnt;

  fused_kernel<<<NBLK, 256, 0, stream>>>(ka);
}